// Round 1
// baseline (150.652 us; speedup 1.0000x reference)
//
#include <hip/hip_runtime.h>

// out[r] = dot(x[r], colsum(W)) + sum(b)
// x: [4096, 4096] f32, W: [4096, 4096] f32 (row-major [OUT][IN]), b: [4096] f32
// ws layout: ws[0..4095] = colsum(W), ws[4096] = sum(b)

#define N 4096
#define N4 1024              // N / 4 (float4 columns)
#define ROWS_PER_CHUNK 64

__global__ void colsum_kernel(const float* __restrict__ W,
                              const float* __restrict__ b,
                              float* __restrict__ ws) {
    const int c4 = blockIdx.x * blockDim.x + threadIdx.x;   // float4 col idx 0..1023
    const int row0 = blockIdx.y * ROWS_PER_CHUNK;
    const float4* W4 = reinterpret_cast<const float4*>(W);

    float4 acc = make_float4(0.f, 0.f, 0.f, 0.f);
#pragma unroll 8
    for (int r = 0; r < ROWS_PER_CHUNK; ++r) {
        float4 v = W4[(size_t)(row0 + r) * N4 + c4];
        acc.x += v.x; acc.y += v.y; acc.z += v.z; acc.w += v.w;
    }
    float* dst = ws + c4 * 4;
    atomicAdd(dst + 0, acc.x);
    atomicAdd(dst + 1, acc.y);
    atomicAdd(dst + 2, acc.z);
    atomicAdd(dst + 3, acc.w);

    if (blockIdx.y == 0) {
        // bias sum: the 4 by==0 blocks (1024 threads) cover all 1024 float4s of b
        const float4 bv = reinterpret_cast<const float4*>(b)[c4];
        float s = bv.x + bv.y + bv.z + bv.w;
#pragma unroll
        for (int off = 32; off > 0; off >>= 1)
            s += __shfl_down(s, off, 64);
        if ((threadIdx.x & 63) == 0)
            atomicAdd(ws + N, s);
    }
}

__global__ void gemv_kernel(const float* __restrict__ x,
                            const float* __restrict__ ws,
                            float* __restrict__ out) {
    const int wave = threadIdx.x >> 6;            // 0..3
    const int lane = threadIdx.x & 63;
    const int row  = blockIdx.x * 4 + wave;       // 0..4095

    const float4* x4 = reinterpret_cast<const float4*>(x) + (size_t)row * N4;
    const float4* w4 = reinterpret_cast<const float4*>(ws);

    float acc = 0.f;
#pragma unroll
    for (int k = 0; k < 16; ++k) {
        float4 xv = x4[lane + k * 64];
        float4 wv = w4[lane + k * 64];
        acc += xv.x * wv.x + xv.y * wv.y + xv.z * wv.z + xv.w * wv.w;
    }
#pragma unroll
    for (int off = 32; off > 0; off >>= 1)
        acc += __shfl_down(acc, off, 64);
    if (lane == 0)
        out[row] = acc + ws[N];
}

extern "C" void kernel_launch(void* const* d_in, const int* in_sizes, int n_in,
                              void* d_out, int out_size, void* d_ws, size_t ws_size,
                              hipStream_t stream) {
    const float* x = (const float*)d_in[0];
    const float* W = (const float*)d_in[1];
    const float* b = (const float*)d_in[2];
    float* out = (float*)d_out;
    float* ws  = (float*)d_ws;

    // zero the accumulation workspace (ws is re-poisoned to 0xAA before every launch)
    hipMemsetAsync(ws, 0, (N + 1) * sizeof(float), stream);

    // column sums of W + bias sum
    colsum_kernel<<<dim3(N4 / 256, N / ROWS_PER_CHUNK), 256, 0, stream>>>(W, b, ws);

    // out = x @ wsum + bsum   (one wave per row)
    gemv_kernel<<<N / 4, 256, 0, stream>>>(x, ws, out);
}